// Round 7
// baseline (335.119 us; speedup 1.0000x reference)
//
#include <hip/hip_runtime.h>
#include <hip/hip_bf16.h>
#include <math.h>

#define B_N 4096
#define M_N 128
#define F_N 32
#define H_N 512
#define NFM 4096   // F*M

// wave-local LDS sync: all lanes of a wave run in lockstep, so a waitcnt on
// outstanding LDS ops makes prior cross-lane LDS writes visible to reads.
#define WAVE_SYNC() do { \
  asm volatile("s_waitcnt lgkmcnt(0)" ::: "memory"); \
  __builtin_amdgcn_sched_barrier(0); \
} while (0)

// ---------------------------------------------------------------------------
// Kernel 1: occupied-index extraction (wave ballot) + hidden layer
//   h[b,:] = tanhf( sum_j W1[idx_j,:] + b1 )   (ascending-j chain, fp32)
// ROUND 18: additionally scatters each occupied (b, orbital c, rank j) into
// per-orbital buckets: pos = atomicAdd(bcnt[c]); bent[c*B_N+pos] = (b<<5)|j.
// Bucket ORDER is nondeterministic (atomics) but only permutes which block
// computes an output — per-output arithmetic is order-independent.
// ---------------------------------------------------------------------------
__global__ __launch_bounds__(256) void k1_idx_h(
    const float* __restrict__ n, const float* __restrict__ W1,
    const float* __restrict__ b1, float* __restrict__ h_ws,
    int* __restrict__ bcnt, int* __restrict__ bent)
{
  __shared__ int s_idx[F_N];
  __shared__ int s_cnt0;
  const int b = blockIdx.x;
  const int t = threadIdx.x;

  bool p = false;
  int before = 0;
  if (t < 128) {
    float v = n[(size_t)b * M_N + t];
    p = v > 0.5f;
    unsigned long long m = __ballot(p);
    int lane = t & 63;
    before = __popcll(m & ((1ull << lane) - 1ull));
    if (t < 64) {
      if (lane == 0) s_cnt0 = __popcll(m);
      if (p) s_idx[before] = t;          // ascending within wave 0
    }
  }
  __syncthreads();
  if (t >= 64 && t < 128 && p) s_idx[s_cnt0 + before] = t;

  // bucket scatter: j = rank of orbital t within sample b (ascending)
  if (t < 128 && p) {
    int j = (t < 64) ? before : (s_cnt0 + before);
    int pos = atomicAdd(&bcnt[t], 1);
    bent[t * B_N + pos] = (b << 5) | j;
  }
  __syncthreads();

  #pragma unroll
  for (int cc = 0; cc < 2; ++cc) {
    int c = t + cc * 256;
    float acc = 0.0f;
    #pragma unroll
    for (int j = 0; j < F_N; ++j)
      acc += W1[(size_t)s_idx[j] * H_N + c];
    acc += b1[c];                        // b1 = zeros: exact
    h_ws[(size_t)b * H_N + c] = tanhf(acc);
  }
}

// ---------------------------------------------------------------------------
// Kernel 2 (ROUND 18 rewrite): BUCKETED GEMM — 4x FLOP cut.
// DIAGNOSIS rounds 0-6: dense 17.2 GFLOP GEMM pinned at ~237 us (VALUBusy
//   ~60%) across occupancy 19/25/35% — structure at its operating point.
//   But the gather uses only 32 of 128 computed columns per ig: 75% of the
//   GEMM is discarded. Bucketing samples by occupied orbital c computes
//   ONLY needed outputs: per bucket c, [cnt_c x 512] @ [512 x 32] panel
//   (cols ig*128+c, ig=0..31). Sum cnt_c = 4096*32 -> 4.3 GFLOP (27us floor).
// Grid (128 buckets x 32 row-tiles of 128), 256 threads, 4x4 micro-tile,
//   BK=16, double-buffered LDS (At[16][132] transposed + Bt[16][32]),
//   one barrier per k-tile — same pipeline structure as rounds 2-6.
//   Empty tiles early-exit (block-uniform). Partial tiles clamp gather rows
//   to a valid entry and guard the writes.
// ARITHMETIC BIT-IDENTICAL: each output (b,ig,j) = one ascending-k fmaf
//   chain (t ascending, kk ascending, single accumulator) over the same
//   h/W2 values; epilogue expression Phi + (acc + b2) unchanged. Each
//   (b,ig,j) written exactly once (its unique bucket c = idx[b][j]).
//   absmax must stay exactly 0.203125.
// ---------------------------------------------------------------------------
__global__ __launch_bounds__(256) void k2_gemm_gather(
    const float* __restrict__ h, const float* __restrict__ W2,
    const float* __restrict__ b2, const float* __restrict__ Phi,
    const int* __restrict__ bcnt, const int* __restrict__ bent,
    float* __restrict__ phi)
{
  // per buffer: At [16][132] = 2112 floats + Bt [16][32] = 512 -> 2624
  __shared__ __align__(16) float smem[2 * 2624];   // 20992 B
  __shared__ int s_b[128], s_j[128];

  const int tid = threadIdx.x;               // 0..255
  const int c   = blockIdx.x;                // orbital 0..127
  const int cnt = bcnt[c];
  const int t0  = blockIdx.y * 128;          // row-tile base within bucket
  if (t0 >= cnt) return;                     // block-uniform early exit

  if (tid < 128) {
    int ii = t0 + tid;
    int e  = bent[c * B_N + (ii < cnt ? ii : cnt - 1)];  // clamp: cnt >= 1
    s_b[tid] = e >> 5;
    s_j[tid] = e & 31;
  }
  __syncthreads();

  const int kA  = tid & 15;                  // A stage: kk (0..15)
  const int rbA = (tid >> 4) * 8;            // A stage: row base (0..120)
  const int kB  = tid >> 5;                  // B stage: k row (0..7)
  const int igB = tid & 31;                  // B stage: ig
  const int tx  = tid & 7;                   // col group: igs tx*4..+3
  const int tyr = tid >> 3;                  // row group 0..31: rows tyr*4..+3

  int rowb[8];
  #pragma unroll
  for (int i = 0; i < 8; ++i) rowb[i] = s_b[rbA + i];

  float acc[4][4];
  #pragma unroll
  for (int i = 0; i < 4; ++i)
    #pragma unroll
    for (int u = 0; u < 4; ++u) acc[i][u] = 0.f;

  float aReg[8], bReg0, bReg1;

  // ---- prologue: stage k-tile 0 into buf0 ----
  #pragma unroll
  for (int i = 0; i < 8; ++i)
    aReg[i] = h[(size_t)rowb[i] * H_N + kA];
  bReg0 = W2[(size_t)kB * NFM + igB * M_N + c];
  bReg1 = W2[(size_t)(kB + 8) * NFM + igB * M_N + c];
  *(float4*)&smem[kA * 132 + rbA] =
      make_float4(aReg[0], aReg[1], aReg[2], aReg[3]);
  *(float4*)&smem[kA * 132 + rbA + 4] =
      make_float4(aReg[4], aReg[5], aReg[6], aReg[7]);
  smem[2112 + kB * 32 + igB] = bReg0;
  smem[2112 + (kB + 8) * 32 + igB] = bReg1;
  __syncthreads();

  #pragma unroll 1
  for (int t = 0; t < 32; ++t) {
    float* Atc = smem + (t & 1) * 2624;
    float* Btc = Atc + 2112;
    float* Atn = smem + ((t + 1) & 1) * 2624;
    float* Btn = Atn + 2112;

    // issue next tile's global loads (latency hides under compute)
    if (t < 31) {
      int k0n = (t + 1) * 16;
      #pragma unroll
      for (int i = 0; i < 8; ++i)
        aReg[i] = h[(size_t)rowb[i] * H_N + k0n + kA];
      bReg0 = W2[(size_t)(k0n + kB) * NFM + igB * M_N + c];
      bReg1 = W2[(size_t)(k0n + kB + 8) * NFM + igB * M_N + c];
    }

    // compute tile t: 2 x ds_read_b128 + 16 fmaf per kk
    #pragma unroll
    for (int kk = 0; kk < 16; ++kk) {
      float4 av = *(const float4*)&Atc[kk * 132 + tyr * 4];
      float4 bv = *(const float4*)&Btc[kk * 32 + tx * 4];
      float a4[4] = {av.x, av.y, av.z, av.w};
      float b4[4] = {bv.x, bv.y, bv.z, bv.w};
      #pragma unroll
      for (int i = 0; i < 4; ++i)
        #pragma unroll
        for (int u = 0; u < 4; ++u)
          acc[i][u] = fmaf(a4[i], b4[u], acc[i][u]);
    }

    // stage tile t+1 into the idle buffer; single barrier flips
    if (t < 31) {
      *(float4*)&Atn[kA * 132 + rbA] =
          make_float4(aReg[0], aReg[1], aReg[2], aReg[3]);
      *(float4*)&Atn[kA * 132 + rbA + 4] =
          make_float4(aReg[4], aReg[5], aReg[6], aReg[7]);
      Btn[kB * 32 + igB] = bReg0;
      Btn[(kB + 8) * 32 + igB] = bReg1;
      __syncthreads();
    }
  }

  // ---- epilogue: direct scattered writes (each (b,ig,j) exactly once) ----
  #pragma unroll
  for (int i = 0; i < 4; ++i) {
    int r = tyr * 4 + i;
    if (t0 + r < cnt) {
      int bb = s_b[r], jj = s_j[r];
      #pragma unroll
      for (int u = 0; u < 4; ++u) {
        int ig  = tx * 4 + u;
        int col = ig * M_N + c;
        float val = Phi[col] + (acc[i][u] + b2[col]);
        phi[(size_t)bb * (F_N * F_N) + ig * F_N + jj] = val;
      }
    }
  }
}

// ---------------------------------------------------------------------------
// Kernel 3: batched 32x32 fp32 LU replicating LAPACK sgetf2 exactly.
// Each matrix is owned by ONE wave working in its private LDS slice, so all
// cross-wave __syncthreads() are replaced with wave-local WAVE_SYNC()
// (s_waitcnt lgkmcnt(0)): the 4 waves per block run fully decoupled.
// Arithmetic sequence per matrix UNCHANGED from rounds 6-11.
// PLANAR complex output: out[0..B-1] = log|det|, out[B..2B-1] = arg(sign)
// ---------------------------------------------------------------------------
__global__ __launch_bounds__(256) void k3_det(
    const float* __restrict__ phi, float* __restrict__ out)
{
  __shared__ float A[4][32 * 33];
  const int w = threadIdx.x >> 6;
  const int lane = threadIdx.x & 63;
  const int b = blockIdx.x * 4 + w;
  float* Aw = A[w];

  #pragma unroll
  for (int u = 0; u < 16; ++u) {
    int lin = u * 64 + lane;
    Aw[(lin >> 5) * 33 + (lin & 31)] = phi[(size_t)b * 1024 + lin];
  }
  WAVE_SYNC();

  float logabs = 0.f;
  int negs = 0;
  for (int k = 0; k < 32; ++k) {
    // isamax over rows k..31 of column k (ties -> first index)
    float v = -1.f;
    int vi = lane;
    if (lane >= k && lane < 32) v = fabsf(Aw[lane * 33 + k]);
    #pragma unroll
    for (int off = 32; off > 0; off >>= 1) {
      float ov = __shfl_xor(v, off);
      int oi = __shfl_xor(vi, off);
      if (ov > v || (ov == v && oi < vi)) { v = ov; vi = oi; }
    }
    int p = vi;                          // uniform across the wave
    if (p != k) {
      negs ^= 1;
      if (lane < 32) {
        float tmp = Aw[k * 33 + lane];
        Aw[k * 33 + lane] = Aw[p * 33 + lane];
        Aw[p * 33 + lane] = tmp;
      }
    }
    WAVE_SYNC();
    float piv = Aw[k * 33 + k];
    if (piv < 0.f) negs ^= 1;
    logabs += logf(fabsf(piv));
    if (lane > k && lane < 32) {
      float l = Aw[lane * 33 + k];
      if (fabsf(piv) >= 1.17549435e-38f) l = l * (1.0f / piv);  // sscal path
      else                               l = l / piv;           // tiny pivot
      Aw[lane * 33 + k] = l;
    }
    WAVE_SYNC();
    if (lane > k && lane < 32) {
      int j = lane;
      float nukj = -Aw[k * 33 + j];
      for (int i = k + 1; i < 32; ++i)
        Aw[i * 33 + j] = fmaf(nukj, Aw[i * 33 + k], Aw[i * 33 + j]);
    }
    WAVE_SYNC();
  }

  if (lane == 0) {
    out[b]       = logabs;                                   // Re: log|det|
    out[B_N + b] = (negs & 1) ? 3.14159265358979f : 0.0f;    // Im: arg(sign)
  }
}

// ---------------------------------------------------------------------------
extern "C" void kernel_launch(void* const* d_in, const int* in_sizes, int n_in,
                              void* d_out, int out_size, void* d_ws, size_t ws_size,
                              hipStream_t stream) {
  const float* n   = (const float*)d_in[0];
  const float* Phi = (const float*)d_in[1];
  const float* W1  = (const float*)d_in[2];
  const float* b1  = (const float*)d_in[3];
  const float* W2  = (const float*)d_in[4];
  const float* b2  = (const float*)d_in[5];
  float* out = (float*)d_out;

  char* ws = (char*)d_ws;
  float* h_ws   = (float*)ws;                                   // 8 MB
  float* phi_ws = (float*)(ws + (size_t)8 * 1024 * 1024);       // 16 MB
  int*   bcnt   = (int*)(ws + (size_t)24 * 1024 * 1024);        // 512 B
  int*   bent   = (int*)(ws + (size_t)24 * 1024 * 1024 + 4096); // 2 MB

  hipMemsetAsync(bcnt, 0, 128 * sizeof(int), stream);
  hipLaunchKernelGGL(k1_idx_h, dim3(B_N), dim3(256), 0, stream,
                     n, W1, b1, h_ws, bcnt, bent);
  hipLaunchKernelGGL(k2_gemm_gather, dim3(128, 32), dim3(256), 0, stream,
                     h_ws, W2, b2, Phi, bcnt, bent, phi_ws);
  hipLaunchKernelGGL(k3_det, dim3(B_N / 4), dim3(256), 0, stream,
                     phi_ws, out);
}

// Round 8
// 243.913 us; speedup vs baseline: 1.3739x; 1.3739x over previous
//
#include <hip/hip_runtime.h>
#include <hip/hip_bf16.h>
#include <math.h>

#define B_N 4096
#define M_N 128
#define F_N 32
#define H_N 512
#define NFM 4096   // F*M

// wave-local LDS sync: all lanes of a wave run in lockstep, so a waitcnt on
// outstanding LDS ops makes prior cross-lane LDS writes visible to reads.
#define WAVE_SYNC() do { \
  asm volatile("s_waitcnt lgkmcnt(0)" ::: "memory"); \
  __builtin_amdgcn_sched_barrier(0); \
} while (0)

// ---------------------------------------------------------------------------
// Kernel 1: occupied-index extraction (wave ballot) + hidden layer.
// ROUND 19: NO ATOMICS (round 18's 131K atomicAdds onto 8 cache lines cost
// ~70 us). Instead writes the 128-bit occupancy mask per sample (straight
// from the two wave ballots); buckets are built deterministically by
// k_count + k_fill, sorted by ascending b.
//   h[b,:] = tanhf( sum_j W1[idx_j,:] + b1 )   (ascending-j chain, fp32)
// ---------------------------------------------------------------------------
__global__ __launch_bounds__(256) void k1_idx_h(
    const float* __restrict__ n, const float* __restrict__ W1,
    const float* __restrict__ b1, float* __restrict__ h_ws,
    unsigned int* __restrict__ mask)
{
  __shared__ int s_idx[F_N];
  __shared__ int s_cnt0;
  const int b = blockIdx.x;
  const int t = threadIdx.x;

  bool p = false;
  int before = 0;
  if (t < 128) {
    float v = n[(size_t)b * M_N + t];
    p = v > 0.5f;
    unsigned long long m = __ballot(p);
    int lane = t & 63;
    before = __popcll(m & ((1ull << lane) - 1ull));
    if (lane == 0) {
      if (t < 64) { mask[b*4+0] = (unsigned)m; mask[b*4+1] = (unsigned)(m>>32); }
      else        { mask[b*4+2] = (unsigned)m; mask[b*4+3] = (unsigned)(m>>32); }
    }
    if (t < 64) {
      if (lane == 0) s_cnt0 = __popcll(m);
      if (p) s_idx[before] = t;          // ascending within wave 0
    }
  }
  __syncthreads();
  if (t >= 64 && t < 128 && p) s_idx[s_cnt0 + before] = t;
  __syncthreads();

  #pragma unroll
  for (int cc = 0; cc < 2; ++cc) {
    int c = t + cc * 256;
    float acc = 0.0f;
    #pragma unroll
    for (int j = 0; j < F_N; ++j)
      acc += W1[(size_t)s_idx[j] * H_N + c];
    acc += b1[c];                        // b1 = zeros: exact
    h_ws[(size_t)b * H_N + c] = tanhf(acc);
  }
}

// ---------------------------------------------------------------------------
// k_count: bcnt[c] = number of samples with orbital c occupied. No atomics.
// ---------------------------------------------------------------------------
__global__ __launch_bounds__(256) void k_count(
    const unsigned int* __restrict__ mask, int* __restrict__ bcnt)
{
  const int c = blockIdx.x;
  const int t = threadIdx.x;
  const int word = c >> 5, bit = c & 31;
  int sum = 0;
  for (int b = t; b < B_N; b += 256)
    sum += (int)((mask[(size_t)b*4 + word] >> bit) & 1u);
  #pragma unroll
  for (int off = 32; off > 0; off >>= 1) sum += __shfl_down(sum, off);
  __shared__ int s_s[4];
  if ((t & 63) == 0) s_s[t >> 6] = sum;
  __syncthreads();
  if (t == 0) bcnt[c] = s_s[0] + s_s[1] + s_s[2] + s_s[3];
}

// ---------------------------------------------------------------------------
// k_fill: deterministic bucket fill, entries sorted by ascending sample b.
//   bent[c*B_N + pos] = (b<<5) | j   (j = rank of c in sample b's occ set)
//   loc[b*32 + j]     = boff[c] + pos   (column index into phi_bucket)
// ---------------------------------------------------------------------------
__global__ __launch_bounds__(256) void k_fill(
    const unsigned int* __restrict__ mask, const int* __restrict__ bcnt,
    int* __restrict__ boff, int* __restrict__ bent, int* __restrict__ loc)
{
  const int c = blockIdx.x;
  const int t = threadIdx.x;
  const int w = t >> 6, lane = t & 63;
  __shared__ int s_wcnt[4];
  __shared__ int s_run;
  __shared__ int s_off;

  if (t == 0) {
    int o = 0;
    for (int i = 0; i < c; ++i) o += bcnt[i];
    s_off = o; boff[c] = o; s_run = 0;
  }
  __syncthreads();
  const int off = s_off;
  const int word = c >> 5, bit = c & 31;

  for (int chunk = 0; chunk < B_N; chunk += 256) {
    const int b = chunk + t;
    unsigned m0 = mask[(size_t)b*4+0], m1 = mask[(size_t)b*4+1];
    unsigned m2 = mask[(size_t)b*4+2], m3 = mask[(size_t)b*4+3];
    unsigned wv = (word == 0) ? m0 : (word == 1) ? m1 : (word == 2) ? m2 : m3;
    bool p = (wv >> bit) & 1u;
    int j = __popc(wv & ((1u << bit) - 1u));
    if (word > 0) j += __popc(m0);
    if (word > 1) j += __popc(m1);
    if (word > 2) j += __popc(m2);

    unsigned long long bal = __ballot(p);
    int before = __popcll(bal & ((1ull << lane) - 1ull));
    if (lane == 0) s_wcnt[w] = __popcll(bal);
    __syncthreads();
    int wbase = s_run;
    for (int i = 0; i < w; ++i) wbase += s_wcnt[i];
    if (p) {
      int pos = wbase + before;              // bucket-local, ascending b
      bent[(size_t)c * B_N + pos] = (b << 5) | j;
      loc[b * 32 + j] = off + pos;
    }
    __syncthreads();
    if (t == 0) s_run += s_wcnt[0] + s_wcnt[1] + s_wcnt[2] + s_wcnt[3];
    __syncthreads();
  }
}

// ---------------------------------------------------------------------------
// Kernel 2 (ROUND 19): BUCKETED GEMM, memory-fixed.
// Round 18 post-mortem: 190 us, VALUBusy 24.5%, FETCH 134 MB, WRITE 161 MB —
//   (a) atomic-ordered buckets made A-row tiles random over 4096 samples
//       (L2 thrash); (b) per-element scattered phi writes amplified 16 MB to
//       161 MB of lines.
// Fixes: entries sorted by b (tile y of EVERY bucket spans the same ~512-
//   sample h window; grid x = bucket is the fast dispatch dim -> co-located
//   L2 reuse) + phi written in bucket-major layout phi_bucket[col*32+ig]
//   (32 contiguous floats per entry, float4-coalesced; k3 gathers via loc).
// GEMM core unchanged from round 18: [cnt_c x 512] @ [512 x 32] per bucket,
//   4x4 micro-tile, BK=16, double-buffered LDS, one barrier per k-tile.
// ARITHMETIC BIT-IDENTICAL: each output (b,ig,j) = one ascending-k fmaf
//   chain (t ascending, kk ascending, single accumulator); epilogue
//   expression Phi + (acc + b2) unchanged; each output written exactly once.
//   absmax must stay exactly 0.203125.
// ---------------------------------------------------------------------------
__global__ __launch_bounds__(256) void k2_gemm_gather(
    const float* __restrict__ h, const float* __restrict__ W2,
    const float* __restrict__ b2, const float* __restrict__ Phi,
    const int* __restrict__ bcnt, const int* __restrict__ boff,
    const int* __restrict__ bent, float* __restrict__ phi_bucket)
{
  // per buffer: At [16][132] = 2112 floats + Bt [16][32] = 512 -> 2624
  __shared__ __align__(16) float smem[2 * 2624];   // 20992 B
  __shared__ int s_b[128];

  const int tid = threadIdx.x;               // 0..255
  const int c   = blockIdx.x;                // orbital 0..127
  const int cnt = bcnt[c];
  const int t0  = blockIdx.y * 128;          // row-tile base within bucket
  if (t0 >= cnt) return;                     // block-uniform early exit
  const int base = boff[c];

  if (tid < 128) {
    int ii = t0 + tid;
    int e  = bent[(size_t)c * B_N + (ii < cnt ? ii : cnt - 1)];  // cnt >= 1
    s_b[tid] = e >> 5;
  }
  __syncthreads();

  const int kA  = tid & 15;                  // A stage: kk (0..15)
  const int rbA = (tid >> 4) * 8;            // A stage: row base (0..120)
  const int kB  = tid >> 5;                  // B stage: k row (0..7)
  const int igB = tid & 31;                  // B stage: ig
  const int tx  = tid & 7;                   // col group: igs tx*4..+3
  const int tyr = tid >> 3;                  // row group 0..31: rows tyr*4..+3

  int rowb[8];
  #pragma unroll
  for (int i = 0; i < 8; ++i) rowb[i] = s_b[rbA + i];

  float acc[4][4];
  #pragma unroll
  for (int i = 0; i < 4; ++i)
    #pragma unroll
    for (int u = 0; u < 4; ++u) acc[i][u] = 0.f;

  float aReg[8], bReg0, bReg1;

  // ---- prologue: stage k-tile 0 into buf0 ----
  #pragma unroll
  for (int i = 0; i < 8; ++i)
    aReg[i] = h[(size_t)rowb[i] * H_N + kA];
  bReg0 = W2[(size_t)kB * NFM + igB * M_N + c];
  bReg1 = W2[(size_t)(kB + 8) * NFM + igB * M_N + c];
  *(float4*)&smem[kA * 132 + rbA] =
      make_float4(aReg[0], aReg[1], aReg[2], aReg[3]);
  *(float4*)&smem[kA * 132 + rbA + 4] =
      make_float4(aReg[4], aReg[5], aReg[6], aReg[7]);
  smem[2112 + kB * 32 + igB] = bReg0;
  smem[2112 + (kB + 8) * 32 + igB] = bReg1;
  __syncthreads();

  #pragma unroll 1
  for (int t = 0; t < 32; ++t) {
    float* Atc = smem + (t & 1) * 2624;
    float* Btc = Atc + 2112;
    float* Atn = smem + ((t + 1) & 1) * 2624;
    float* Btn = Atn + 2112;

    // issue next tile's global loads (latency hides under compute)
    if (t < 31) {
      int k0n = (t + 1) * 16;
      #pragma unroll
      for (int i = 0; i < 8; ++i)
        aReg[i] = h[(size_t)rowb[i] * H_N + k0n + kA];
      bReg0 = W2[(size_t)(k0n + kB) * NFM + igB * M_N + c];
      bReg1 = W2[(size_t)(k0n + kB + 8) * NFM + igB * M_N + c];
    }

    // compute tile t: 2 x ds_read_b128 + 16 fmaf per kk
    #pragma unroll
    for (int kk = 0; kk < 16; ++kk) {
      float4 av = *(const float4*)&Atc[kk * 132 + tyr * 4];
      float4 bv = *(const float4*)&Btc[kk * 32 + tx * 4];
      float a4[4] = {av.x, av.y, av.z, av.w};
      float b4[4] = {bv.x, bv.y, bv.z, bv.w};
      #pragma unroll
      for (int i = 0; i < 4; ++i)
        #pragma unroll
        for (int u = 0; u < 4; ++u)
          acc[i][u] = fmaf(a4[i], b4[u], acc[i][u]);
    }

    // stage tile t+1 into the idle buffer; single barrier flips
    if (t < 31) {
      *(float4*)&Atn[kA * 132 + rbA] =
          make_float4(aReg[0], aReg[1], aReg[2], aReg[3]);
      *(float4*)&Atn[kA * 132 + rbA + 4] =
          make_float4(aReg[4], aReg[5], aReg[6], aReg[7]);
      Btn[kB * 32 + igB] = bReg0;
      Btn[(kB + 8) * 32 + igB] = bReg1;
      __syncthreads();
    }
  }

  // ---- epilogue: coalesced float4 writes into bucket-major phi ----
  #pragma unroll
  for (int i = 0; i < 4; ++i) {
    int r = tyr * 4 + i;
    if (t0 + r < cnt) {
      int col = base + t0 + r;               // global column index
      float v[4];
      #pragma unroll
      for (int u = 0; u < 4; ++u) {
        int ig   = tx * 4 + u;
        int colw = ig * M_N + c;
        v[u] = Phi[colw] + (acc[i][u] + b2[colw]);
      }
      *(float4*)&phi_bucket[(size_t)col * 32 + tx * 4] =
          make_float4(v[0], v[1], v[2], v[3]);
    }
  }
}

// ---------------------------------------------------------------------------
// Kernel 3: batched 32x32 fp32 LU replicating LAPACK sgetf2 exactly.
// ROUND 19: loads matrix columns from bucket-major phi_bucket via loc:
//   column j of sample b lives at phi_bucket[loc[b*32+j]*32 + ig], ig=0..31
//   (contiguous 128 B). Arithmetic sequence per matrix UNCHANGED.
// PLANAR complex output: out[0..B-1] = log|det|, out[B..2B-1] = arg(sign)
// ---------------------------------------------------------------------------
__global__ __launch_bounds__(256) void k3_det(
    const float* __restrict__ phi_bucket, const int* __restrict__ loc,
    float* __restrict__ out)
{
  __shared__ float A[4][32 * 33];
  const int w = threadIdx.x >> 6;
  const int lane = threadIdx.x & 63;
  const int b = blockIdx.x * 4 + w;
  float* Aw = A[w];

  {
    const int jj = lane & 31;
    const int hi = lane >> 5;              // 0 or 1: ig halves
    int lcol = loc[b * 32 + jj];
    const float* colp = phi_bucket + (size_t)lcol * 32 + hi * 16;
    #pragma unroll
    for (int i = 0; i < 4; ++i) {
      float4 v = *(const float4*)(colp + i * 4);
      int ig = hi * 16 + i * 4;
      Aw[(ig + 0) * 33 + jj] = v.x;
      Aw[(ig + 1) * 33 + jj] = v.y;
      Aw[(ig + 2) * 33 + jj] = v.z;
      Aw[(ig + 3) * 33 + jj] = v.w;
    }
  }
  WAVE_SYNC();

  float logabs = 0.f;
  int negs = 0;
  for (int k = 0; k < 32; ++k) {
    // isamax over rows k..31 of column k (ties -> first index)
    float v = -1.f;
    int vi = lane;
    if (lane >= k && lane < 32) v = fabsf(Aw[lane * 33 + k]);
    #pragma unroll
    for (int off = 32; off > 0; off >>= 1) {
      float ov = __shfl_xor(v, off);
      int oi = __shfl_xor(vi, off);
      if (ov > v || (ov == v && oi < vi)) { v = ov; vi = oi; }
    }
    int p = vi;                          // uniform across the wave
    if (p != k) {
      negs ^= 1;
      if (lane < 32) {
        float tmp = Aw[k * 33 + lane];
        Aw[k * 33 + lane] = Aw[p * 33 + lane];
        Aw[p * 33 + lane] = tmp;
      }
    }
    WAVE_SYNC();
    float piv = Aw[k * 33 + k];
    if (piv < 0.f) negs ^= 1;
    logabs += logf(fabsf(piv));
    if (lane > k && lane < 32) {
      float l = Aw[lane * 33 + k];
      if (fabsf(piv) >= 1.17549435e-38f) l = l * (1.0f / piv);  // sscal path
      else                               l = l / piv;           // tiny pivot
      Aw[lane * 33 + k] = l;
    }
    WAVE_SYNC();
    if (lane > k && lane < 32) {
      int j = lane;
      float nukj = -Aw[k * 33 + j];
      for (int i = k + 1; i < 32; ++i)
        Aw[i * 33 + j] = fmaf(nukj, Aw[i * 33 + k], Aw[i * 33 + j]);
    }
    WAVE_SYNC();
  }

  if (lane == 0) {
    out[b]       = logabs;                                   // Re: log|det|
    out[B_N + b] = (negs & 1) ? 3.14159265358979f : 0.0f;    // Im: arg(sign)
  }
}

// ---------------------------------------------------------------------------
extern "C" void kernel_launch(void* const* d_in, const int* in_sizes, int n_in,
                              void* d_out, int out_size, void* d_ws, size_t ws_size,
                              hipStream_t stream) {
  const float* n   = (const float*)d_in[0];
  const float* Phi = (const float*)d_in[1];
  const float* W1  = (const float*)d_in[2];
  const float* b1  = (const float*)d_in[3];
  const float* W2  = (const float*)d_in[4];
  const float* b2  = (const float*)d_in[5];
  float* out = (float*)d_out;

  char* ws = (char*)d_ws;
  float*        h_ws       = (float*)ws;                                  // 8 MB
  float*        phi_bucket = (float*)(ws + (size_t)8  * 1024 * 1024);     // 16 MB
  unsigned int* mask       = (unsigned int*)(ws + (size_t)24 * 1024 * 1024); // 64 KB
  int*          bent       = (int*)(ws + (size_t)24 * 1024 * 1024 + 65536);  // 2 MB
  int*          loc        = (int*)(ws + (size_t)26 * 1024 * 1024 + 65536);  // 512 KB
  int*          bcnt       = (int*)(ws + (size_t)26 * 1024 * 1024 + 65536 + 524288);
  int*          boff       = (int*)(ws + (size_t)26 * 1024 * 1024 + 65536 + 524288 + 4096);

  hipLaunchKernelGGL(k1_idx_h, dim3(B_N), dim3(256), 0, stream,
                     n, W1, b1, h_ws, mask);
  hipLaunchKernelGGL(k_count, dim3(M_N), dim3(256), 0, stream, mask, bcnt);
  hipLaunchKernelGGL(k_fill, dim3(M_N), dim3(256), 0, stream,
                     mask, bcnt, boff, bent, loc);
  hipLaunchKernelGGL(k2_gemm_gather, dim3(M_N, 32), dim3(256), 0, stream,
                     h_ws, W2, b2, Phi, bcnt, boff, bent, phi_bucket);
  hipLaunchKernelGGL(k3_det, dim3(B_N / 4), dim3(256), 0, stream,
                     phi_bucket, loc, out);
}

// Round 9
// 198.598 us; speedup vs baseline: 1.6874x; 1.2282x over previous
//
#include <hip/hip_runtime.h>
#include <hip/hip_bf16.h>
#include <math.h>

#define B_N 4096
#define M_N 128
#define F_N 32
#define H_N 512
#define NFM 4096   // F*M

// wave-local LDS sync: all lanes of a wave run in lockstep, so a waitcnt on
// outstanding LDS ops makes prior cross-lane LDS writes visible to reads.
#define WAVE_SYNC() do { \
  asm volatile("s_waitcnt lgkmcnt(0)" ::: "memory"); \
  __builtin_amdgcn_sched_barrier(0); \
} while (0)

// ---------------------------------------------------------------------------
// Kernel 1: occupied-index extraction (wave ballot) + hidden layer.
// No atomics: writes the 128-bit occupancy mask per sample; buckets built
// deterministically by k_count + k_fill, sorted by ascending b.
//   h[b,:] = tanhf( sum_j W1[idx_j,:] + b1 )   (ascending-j chain, fp32)
// ---------------------------------------------------------------------------
__global__ __launch_bounds__(256) void k1_idx_h(
    const float* __restrict__ n, const float* __restrict__ W1,
    const float* __restrict__ b1, float* __restrict__ h_ws,
    unsigned int* __restrict__ mask)
{
  __shared__ int s_idx[F_N];
  __shared__ int s_cnt0;
  const int b = blockIdx.x;
  const int t = threadIdx.x;

  bool p = false;
  int before = 0;
  if (t < 128) {
    float v = n[(size_t)b * M_N + t];
    p = v > 0.5f;
    unsigned long long m = __ballot(p);
    int lane = t & 63;
    before = __popcll(m & ((1ull << lane) - 1ull));
    if (lane == 0) {
      if (t < 64) { mask[b*4+0] = (unsigned)m; mask[b*4+1] = (unsigned)(m>>32); }
      else        { mask[b*4+2] = (unsigned)m; mask[b*4+3] = (unsigned)(m>>32); }
    }
    if (t < 64) {
      if (lane == 0) s_cnt0 = __popcll(m);
      if (p) s_idx[before] = t;          // ascending within wave 0
    }
  }
  __syncthreads();
  if (t >= 64 && t < 128 && p) s_idx[s_cnt0 + before] = t;
  __syncthreads();

  #pragma unroll
  for (int cc = 0; cc < 2; ++cc) {
    int c = t + cc * 256;
    float acc = 0.0f;
    #pragma unroll
    for (int j = 0; j < F_N; ++j)
      acc += W1[(size_t)s_idx[j] * H_N + c];
    acc += b1[c];                        // b1 = zeros: exact
    h_ws[(size_t)b * H_N + c] = tanhf(acc);
  }
}

// ---------------------------------------------------------------------------
// k_w2t (ROUND 20): pre-transpose W2 into bucket-friendly layout:
//   W2t[c*H_N*F_N + k*F_N + ig] = W2[k*NFM + ig*M_N + c]
// Round 19 post-mortem: the in-k2 W2 column gather read 16K elements/bucket
// each on its OWN 64 B line -> 1 MB lines/bucket x 128 = 128 MB FETCH (the
// whole measured 132 MB), HBM-latency-stalled (VALUBusy 24%). After this
// transpose each bucket's B panel is 64 KB CONTIGUOUS (L2-resident).
// One block per k: coalesced row read -> LDS [32][132] -> per-c float4
// writes (full 128 B lines per c).
// ---------------------------------------------------------------------------
__global__ __launch_bounds__(256) void k_w2t(
    const float* __restrict__ W2, float* __restrict__ W2t)
{
  __shared__ float lds[32 * 132];
  const int k = blockIdx.x;
  const int t = threadIdx.x;

  #pragma unroll
  for (int i = 0; i < 4; ++i) {
    int m0 = i * 1024 + t * 4;             // never crosses a 128 boundary
    float4 v = *(const float4*)&W2[(size_t)k * NFM + m0];
    int ig = m0 >> 7, c = m0 & 127;
    lds[ig * 132 + c + 0] = v.x;
    lds[ig * 132 + c + 1] = v.y;
    lds[ig * 132 + c + 2] = v.z;
    lds[ig * 132 + c + 3] = v.w;
  }
  __syncthreads();

  const int c  = t >> 1;
  const int ih = (t & 1) * 16;
  float* outp = W2t + (size_t)c * (H_N * F_N) + k * F_N + ih;
  #pragma unroll
  for (int i = 0; i < 4; ++i) {
    int ig = ih + i * 4;
    float4 v = make_float4(lds[(ig + 0) * 132 + c], lds[(ig + 1) * 132 + c],
                           lds[(ig + 2) * 132 + c], lds[(ig + 3) * 132 + c]);
    *(float4*)(outp + i * 4) = v;
  }
}

// ---------------------------------------------------------------------------
// k_count: bcnt[c] = number of samples with orbital c occupied. No atomics.
// ---------------------------------------------------------------------------
__global__ __launch_bounds__(256) void k_count(
    const unsigned int* __restrict__ mask, int* __restrict__ bcnt)
{
  const int c = blockIdx.x;
  const int t = threadIdx.x;
  const int word = c >> 5, bit = c & 31;
  int sum = 0;
  for (int b = t; b < B_N; b += 256)
    sum += (int)((mask[(size_t)b*4 + word] >> bit) & 1u);
  #pragma unroll
  for (int off = 32; off > 0; off >>= 1) sum += __shfl_down(sum, off);
  __shared__ int s_s[4];
  if ((t & 63) == 0) s_s[t >> 6] = sum;
  __syncthreads();
  if (t == 0) bcnt[c] = s_s[0] + s_s[1] + s_s[2] + s_s[3];
}

// ---------------------------------------------------------------------------
// k_fill: deterministic bucket fill, entries sorted by ascending sample b.
//   bent[c*B_N + pos] = (b<<5) | j   (j = rank of c in sample b's occ set)
//   loc[b*32 + j]     = boff[c] + pos   (column index into phi_bucket)
// ---------------------------------------------------------------------------
__global__ __launch_bounds__(256) void k_fill(
    const unsigned int* __restrict__ mask, const int* __restrict__ bcnt,
    int* __restrict__ boff, int* __restrict__ bent, int* __restrict__ loc)
{
  const int c = blockIdx.x;
  const int t = threadIdx.x;
  const int w = t >> 6, lane = t & 63;
  __shared__ int s_wcnt[4];
  __shared__ int s_run;
  __shared__ int s_off;

  if (t == 0) {
    int o = 0;
    for (int i = 0; i < c; ++i) o += bcnt[i];
    s_off = o; boff[c] = o; s_run = 0;
  }
  __syncthreads();
  const int off = s_off;
  const int word = c >> 5, bit = c & 31;

  for (int chunk = 0; chunk < B_N; chunk += 256) {
    const int b = chunk + t;
    unsigned m0 = mask[(size_t)b*4+0], m1 = mask[(size_t)b*4+1];
    unsigned m2 = mask[(size_t)b*4+2], m3 = mask[(size_t)b*4+3];
    unsigned wv = (word == 0) ? m0 : (word == 1) ? m1 : (word == 2) ? m2 : m3;
    bool p = (wv >> bit) & 1u;
    int j = __popc(wv & ((1u << bit) - 1u));
    if (word > 0) j += __popc(m0);
    if (word > 1) j += __popc(m1);
    if (word > 2) j += __popc(m2);

    unsigned long long bal = __ballot(p);
    int before = __popcll(bal & ((1ull << lane) - 1ull));
    if (lane == 0) s_wcnt[w] = __popcll(bal);
    __syncthreads();
    int wbase = s_run;
    for (int i = 0; i < w; ++i) wbase += s_wcnt[i];
    if (p) {
      int pos = wbase + before;              // bucket-local, ascending b
      bent[(size_t)c * B_N + pos] = (b << 5) | j;
      loc[b * 32 + j] = off + pos;
    }
    __syncthreads();
    if (t == 0) s_run += s_wcnt[0] + s_wcnt[1] + s_wcnt[2] + s_wcnt[3];
    __syncthreads();
  }
}

// ---------------------------------------------------------------------------
// Kernel 2 (ROUND 20): BUCKETED GEMM with pre-transposed B panels.
// Per bucket c: [cnt_c x 512] @ [512 x 32], B = W2t + c*16384 (contiguous,
// L2-resident). B-stage is now a LINEAR coalesced copy. A-stage, 4x4
// micro-tile, BK=16, double-buffered LDS, one barrier per k-tile, b-sorted
// entries, bucket-major phi writes — all unchanged from round 19.
// ARITHMETIC BIT-IDENTICAL: B values identical (W2t[c][k][ig] =
// W2[k][ig*128+c]); each output = one ascending-k fmaf chain (t ascending,
// kk ascending, single accumulator); epilogue Phi + (acc + b2) unchanged.
// absmax must stay exactly 0.203125.
// ---------------------------------------------------------------------------
__global__ __launch_bounds__(256) void k2_gemm_gather(
    const float* __restrict__ h, const float* __restrict__ W2t,
    const float* __restrict__ b2, const float* __restrict__ Phi,
    const int* __restrict__ bcnt, const int* __restrict__ boff,
    const int* __restrict__ bent, float* __restrict__ phi_bucket)
{
  // per buffer: At [16][132] = 2112 floats + Bt [16][32] = 512 -> 2624
  __shared__ __align__(16) float smem[2 * 2624];   // 20992 B
  __shared__ int s_b[128];

  const int tid = threadIdx.x;               // 0..255
  const int c   = blockIdx.x;                // orbital 0..127
  const int cnt = bcnt[c];
  const int t0  = blockIdx.y * 128;          // row-tile base within bucket
  if (t0 >= cnt) return;                     // block-uniform early exit
  const int base = boff[c];
  const float* w2tc = W2t + (size_t)c * (H_N * F_N);

  if (tid < 128) {
    int ii = t0 + tid;
    int e  = bent[(size_t)c * B_N + (ii < cnt ? ii : cnt - 1)];  // cnt >= 1
    s_b[tid] = e >> 5;
  }
  __syncthreads();

  const int kA  = tid & 15;                  // A stage: kk (0..15)
  const int rbA = (tid >> 4) * 8;            // A stage: row base (0..120)
  const int tx  = tid & 7;                   // col group: igs tx*4..+3
  const int tyr = tid >> 3;                  // row group 0..31: rows tyr*4..+3

  int rowb[8];
  #pragma unroll
  for (int i = 0; i < 8; ++i) rowb[i] = s_b[rbA + i];

  float acc[4][4];
  #pragma unroll
  for (int i = 0; i < 4; ++i)
    #pragma unroll
    for (int u = 0; u < 4; ++u) acc[i][u] = 0.f;

  float aReg[8], bReg0, bReg1;

  // ---- prologue: stage k-tile 0 into buf0 ----
  #pragma unroll
  for (int i = 0; i < 8; ++i)
    aReg[i] = h[(size_t)rowb[i] * H_N + kA];
  bReg0 = w2tc[tid];                         // rows 0..7  of Bt (linear)
  bReg1 = w2tc[256 + tid];                   // rows 8..15 of Bt
  *(float4*)&smem[kA * 132 + rbA] =
      make_float4(aReg[0], aReg[1], aReg[2], aReg[3]);
  *(float4*)&smem[kA * 132 + rbA + 4] =
      make_float4(aReg[4], aReg[5], aReg[6], aReg[7]);
  smem[2112 + tid] = bReg0;
  smem[2112 + 256 + tid] = bReg1;
  __syncthreads();

  #pragma unroll 1
  for (int t = 0; t < 32; ++t) {
    float* Atc = smem + (t & 1) * 2624;
    float* Btc = Atc + 2112;
    float* Atn = smem + ((t + 1) & 1) * 2624;
    float* Btn = Atn + 2112;

    // issue next tile's global loads (latency hides under compute)
    if (t < 31) {
      int k0n = (t + 1) * 16;
      #pragma unroll
      for (int i = 0; i < 8; ++i)
        aReg[i] = h[(size_t)rowb[i] * H_N + k0n + kA];
      bReg0 = w2tc[k0n * 32 + tid];
      bReg1 = w2tc[k0n * 32 + 256 + tid];
    }

    // compute tile t: 2 x ds_read_b128 + 16 fmaf per kk
    #pragma unroll
    for (int kk = 0; kk < 16; ++kk) {
      float4 av = *(const float4*)&Atc[kk * 132 + tyr * 4];
      float4 bv = *(const float4*)&Btc[kk * 32 + tx * 4];
      float a4[4] = {av.x, av.y, av.z, av.w};
      float b4[4] = {bv.x, bv.y, bv.z, bv.w};
      #pragma unroll
      for (int i = 0; i < 4; ++i)
        #pragma unroll
        for (int u = 0; u < 4; ++u)
          acc[i][u] = fmaf(a4[i], b4[u], acc[i][u]);
    }

    // stage tile t+1 into the idle buffer; single barrier flips
    if (t < 31) {
      *(float4*)&Atn[kA * 132 + rbA] =
          make_float4(aReg[0], aReg[1], aReg[2], aReg[3]);
      *(float4*)&Atn[kA * 132 + rbA + 4] =
          make_float4(aReg[4], aReg[5], aReg[6], aReg[7]);
      Btn[tid] = bReg0;
      Btn[256 + tid] = bReg1;
      __syncthreads();
    }
  }

  // ---- epilogue: coalesced float4 writes into bucket-major phi ----
  #pragma unroll
  for (int i = 0; i < 4; ++i) {
    int r = tyr * 4 + i;
    if (t0 + r < cnt) {
      int col = base + t0 + r;               // global column index
      float v[4];
      #pragma unroll
      for (int u = 0; u < 4; ++u) {
        int ig   = tx * 4 + u;
        int colw = ig * M_N + c;
        v[u] = Phi[colw] + (acc[i][u] + b2[colw]);
      }
      *(float4*)&phi_bucket[(size_t)col * 32 + tx * 4] =
          make_float4(v[0], v[1], v[2], v[3]);
    }
  }
}

// ---------------------------------------------------------------------------
// Kernel 3: batched 32x32 fp32 LU replicating LAPACK sgetf2 exactly.
// Loads matrix columns from bucket-major phi_bucket via loc (contiguous
// 128 B per column). Arithmetic sequence per matrix UNCHANGED.
// PLANAR complex output: out[0..B-1] = log|det|, out[B..2B-1] = arg(sign)
// ---------------------------------------------------------------------------
__global__ __launch_bounds__(256) void k3_det(
    const float* __restrict__ phi_bucket, const int* __restrict__ loc,
    float* __restrict__ out)
{
  __shared__ float A[4][32 * 33];
  const int w = threadIdx.x >> 6;
  const int lane = threadIdx.x & 63;
  const int b = blockIdx.x * 4 + w;
  float* Aw = A[w];

  {
    const int jj = lane & 31;
    const int hi = lane >> 5;              // 0 or 1: ig halves
    int lcol = loc[b * 32 + jj];
    const float* colp = phi_bucket + (size_t)lcol * 32 + hi * 16;
    #pragma unroll
    for (int i = 0; i < 4; ++i) {
      float4 v = *(const float4*)(colp + i * 4);
      int ig = hi * 16 + i * 4;
      Aw[(ig + 0) * 33 + jj] = v.x;
      Aw[(ig + 1) * 33 + jj] = v.y;
      Aw[(ig + 2) * 33 + jj] = v.z;
      Aw[(ig + 3) * 33 + jj] = v.w;
    }
  }
  WAVE_SYNC();

  float logabs = 0.f;
  int negs = 0;
  for (int k = 0; k < 32; ++k) {
    // isamax over rows k..31 of column k (ties -> first index)
    float v = -1.f;
    int vi = lane;
    if (lane >= k && lane < 32) v = fabsf(Aw[lane * 33 + k]);
    #pragma unroll
    for (int off = 32; off > 0; off >>= 1) {
      float ov = __shfl_xor(v, off);
      int oi = __shfl_xor(vi, off);
      if (ov > v || (ov == v && oi < vi)) { v = ov; vi = oi; }
    }
    int p = vi;                          // uniform across the wave
    if (p != k) {
      negs ^= 1;
      if (lane < 32) {
        float tmp = Aw[k * 33 + lane];
        Aw[k * 33 + lane] = Aw[p * 33 + lane];
        Aw[p * 33 + lane] = tmp;
      }
    }
    WAVE_SYNC();
    float piv = Aw[k * 33 + k];
    if (piv < 0.f) negs ^= 1;
    logabs += logf(fabsf(piv));
    if (lane > k && lane < 32) {
      float l = Aw[lane * 33 + k];
      if (fabsf(piv) >= 1.17549435e-38f) l = l * (1.0f / piv);  // sscal path
      else                               l = l / piv;           // tiny pivot
      Aw[lane * 33 + k] = l;
    }
    WAVE_SYNC();
    if (lane > k && lane < 32) {
      int j = lane;
      float nukj = -Aw[k * 33 + j];
      for (int i = k + 1; i < 32; ++i)
        Aw[i * 33 + j] = fmaf(nukj, Aw[i * 33 + k], Aw[i * 33 + j]);
    }
    WAVE_SYNC();
  }

  if (lane == 0) {
    out[b]       = logabs;                                   // Re: log|det|
    out[B_N + b] = (negs & 1) ? 3.14159265358979f : 0.0f;    // Im: arg(sign)
  }
}

// ---------------------------------------------------------------------------
extern "C" void kernel_launch(void* const* d_in, const int* in_sizes, int n_in,
                              void* d_out, int out_size, void* d_ws, size_t ws_size,
                              hipStream_t stream) {
  const float* n   = (const float*)d_in[0];
  const float* Phi = (const float*)d_in[1];
  const float* W1  = (const float*)d_in[2];
  const float* b1  = (const float*)d_in[3];
  const float* W2  = (const float*)d_in[4];
  const float* b2  = (const float*)d_in[5];
  float* out = (float*)d_out;

  char* ws = (char*)d_ws;
  float*        h_ws       = (float*)ws;                                  // 8 MB
  float*        phi_bucket = (float*)(ws + (size_t)8  * 1024 * 1024);     // 16 MB
  float*        W2t        = (float*)(ws + (size_t)24 * 1024 * 1024);     // 8 MB
  unsigned int* mask       = (unsigned int*)(ws + (size_t)32 * 1024 * 1024); // 64 KB
  int*          bent       = (int*)(ws + (size_t)32 * 1024 * 1024 + 65536);  // 2 MB
  int*          loc        = (int*)(ws + (size_t)34 * 1024 * 1024 + 65536);  // 512 KB
  int*          bcnt       = (int*)(ws + (size_t)34 * 1024 * 1024 + 65536 + 524288);
  int*          boff       = (int*)(ws + (size_t)34 * 1024 * 1024 + 65536 + 524288 + 4096);

  hipLaunchKernelGGL(k_w2t, dim3(H_N), dim3(256), 0, stream, W2, W2t);
  hipLaunchKernelGGL(k1_idx_h, dim3(B_N), dim3(256), 0, stream,
                     n, W1, b1, h_ws, mask);
  hipLaunchKernelGGL(k_count, dim3(M_N), dim3(256), 0, stream, mask, bcnt);
  hipLaunchKernelGGL(k_fill, dim3(M_N), dim3(256), 0, stream,
                     mask, bcnt, boff, bent, loc);
  hipLaunchKernelGGL(k2_gemm_gather, dim3(M_N, 32), dim3(256), 0, stream,
                     h_ws, W2t, b2, Phi, bcnt, boff, bent, phi_bucket);
  hipLaunchKernelGGL(k3_det, dim3(B_N / 4), dim3(256), 0, stream,
                     phi_bucket, loc, out);
}